// Round 10
// baseline (9558.922 us; speedup 1.0000x reference)
//
#include <hip/hip_runtime.h>
#include <hip/hip_bf16.h>

// ---------- types ----------
typedef short    bf16x8 __attribute__((ext_vector_type(8)));   // 8 bf16 (4 VGPRs), MFMA A/B frag
typedef float    f32x4  __attribute__((ext_vector_type(4)));   // MFMA C/D frag
typedef unsigned short u16x8 __attribute__((ext_vector_type(8)));

#define B_  64
#define S_  128
#define T_  128
#define E_  1024
#define H_  1024
#define NBLK 256

#define RLX __ATOMIC_RELAXED
#define AGT __HIP_MEMORY_SCOPE_AGENT

__device__ __forceinline__ unsigned short f2bf(float f) {
    unsigned u = __float_as_uint(f);
    unsigned r = (u + 0x7FFFu + ((u >> 16) & 1u)) >> 16;   // RNE
    return (unsigned short)r;
}
__device__ __forceinline__ float bf2f(unsigned short u) {
    return __uint_as_float((unsigned)u << 16);
}
__device__ __forceinline__ float my_tanh(float x) {
    float e = __expf(2.0f * x);
    return 1.0f - 2.0f / (e + 1.0f);
}
__device__ __forceinline__ float my_sig(float x) {
    return 1.0f / (1.0f + __expf(-x));
}

// ---------- coherent (L2-bypass) relaxed accessors ----------
__device__ __forceinline__ void st8c(void* p, unsigned long long v) {
    __hip_atomic_store((unsigned long long*)p, v, RLX, AGT);
}
__device__ __forceinline__ unsigned long long ld8c(const void* p) {
    return __hip_atomic_load((const unsigned long long*)p, RLX, AGT);
}
__device__ __forceinline__ void st4c(void* p, unsigned v) {
    __hip_atomic_store((unsigned*)p, v, RLX, AGT);
}
__device__ __forceinline__ void st4f(void* p, float v) {
    __hip_atomic_store((float*)p, v, RLX, AGT);
}
__device__ __forceinline__ float ld4f(const void* p) {
    return __hip_atomic_load((const float*)p, RLX, AGT);
}

// ---------- 2-level grid barrier: 32 leaves x 8, relaxed atomics only ----------
__device__ __forceinline__ void gbar(int* sync, int g, int ord) {
    __syncthreads();                         // drains vmcnt -> sc1 stores at coherence point
    if (threadIdx.x == 0) {
        int* lc = sync + 64 + (g >> 3) * 64;
        int* lg = lc + 32;
        if (__hip_atomic_fetch_add(lc, 1, RLX, AGT) == 8 * ord - 1) {
            if (__hip_atomic_fetch_add(sync, 1, RLX, AGT) == 32 * ord - 1) {
                __hip_atomic_store(sync + 32, ord, RLX, AGT);
            } else {
                while (__hip_atomic_load(sync + 32, RLX, AGT) < ord)
                    __builtin_amdgcn_s_sleep(2);
            }
            __hip_atomic_store(lg, ord, RLX, AGT);
        } else {
            while (__hip_atomic_load(lg, RLX, AGT) < ord)
                __builtin_amdgcn_s_sleep(2);
        }
    }
    __syncthreads();
}

// ---------- f32 -> bf16 conversion ----------
__global__ void k_cvt(const float* __restrict__ s, unsigned short* __restrict__ d, long n) {
    long i = ((long)blockIdx.x * blockDim.x + threadIdx.x) * 4;
    if (i >= n) return;
    float4 f = *(const float4*)(s + i);
    ushort4 o;
    o.x = f2bf(f.x); o.y = f2bf(f.y); o.z = f2bf(f.z); o.w = f2bf(f.w);
    *(ushort4*)(d + i) = o;
}

// trg_embed (B,T,1024) -> preC[(b*T+t)*4096 + 0..1023]
__global__ void k_cvt_te(const float* __restrict__ s, unsigned short* __restrict__ d, long n) {
    long i = ((long)blockIdx.x * blockDim.x + threadIdx.x) * 4;
    if (i >= n) return;
    float4 f = *(const float4*)(s + i);
    long row = i >> 10, col = i & 1023;
    ushort4 o;
    o.x = f2bf(f.x); o.y = f2bf(f.y); o.z = f2bf(f.z); o.w = f2bf(f.w);
    *(ushort4*)(d + row * 4096 + col) = o;
}

// ---------- generic MFMA GEMM: C[M,N] = A[M,K] @ W[N,K]^T ----------
template<int OUTBF>
__global__ __launch_bounds__(256) void k_gemm(const unsigned short* __restrict__ A, long lda,
                                              const unsigned short* __restrict__ W, long ldw,
                                              void* __restrict__ Cv, long ldc, int K) {
    const int lane = threadIdx.x & 63;
    const int wv   = threadIdx.x >> 6;
    const int r    = lane & 15, g = lane >> 4;
    const long m0  = (long)blockIdx.y * 64 + wv * 16;
    const long n0  = (long)blockIdx.x * 64;
    const unsigned short* a  = A + (m0 + r) * lda + g * 8;
    const unsigned short* w0 = W + (n0 + r) * ldw + g * 8;
    f32x4 acc[4] = {};
    for (int k = 0; k < K; k += 32) {
        bf16x8 av = *(const bf16x8*)(a + k);
#pragma unroll
        for (int j = 0; j < 4; ++j) {
            bf16x8 bv = *(const bf16x8*)(w0 + (long)j * 16 * ldw + k);
            acc[j] = __builtin_amdgcn_mfma_f32_16x16x32_bf16(av, bv, acc[j], 0, 0, 0);
        }
    }
#pragma unroll
    for (int j = 0; j < 4; ++j) {
        long row = m0 + g * 4;
        long col = n0 + j * 16 + r;
#pragma unroll
        for (int rr = 0; rr < 4; ++rr) {
            float v = acc[j][rr];
            if (OUTBF) ((unsigned short*)Cv)[(row + rr) * ldc + col] = f2bf(v);
            else       ((float*)Cv)[(row + rr) * ldc + col] = v;
        }
    }
}

// ---------- h0 activation ----------
__global__ void k_h0act(const float* __restrict__ hp, const float* __restrict__ bb,
                        float* __restrict__ h, unsigned short* __restrict__ hbf) {
    int i = blockIdx.x * 256 + threadIdx.x;   // 65536
    float v = my_tanh(hp[i] + bb[i & 1023]);
    h[i] = v; hbf[i] = f2bf(v);
}

// ---------- persistent step loop: 256 blocks x 1024 thr, 3 barriers/step ----------
// Round-6 skeleton; P2 energy+ctx use 16B loads, ctx reduces in-wave (no LDS staging).
__global__ __launch_bounds__(1024) void k_steps(
        const unsigned short* __restrict__ pk, const unsigned short* __restrict__ eh,
        const unsigned short* __restrict__ whp, const unsigned short* __restrict__ wih,
        const float* __restrict__ We, const float* __restrict__ gix,
        const float* __restrict__ bih, const float* __restrict__ bhh,
        const float* __restrict__ h0f, const unsigned short* __restrict__ hbf,
        float* __restrict__ hp, unsigned short* __restrict__ preC,
        float* __restrict__ o_states, float* __restrict__ o_hf,
        int* __restrict__ sync) {
    __shared__ float smf[16 * 64 * 4];        // P1/P3 MFMA staging (16 KB)
    __shared__ float epart[256];              // P2 energy partials
    __shared__ float alr[132];                // P2 alphas 128 + red 4
    __shared__ unsigned short hsm[256];
    const int g    = blockIdx.x;
    const int tid  = threadIdx.x;
    const int wv   = tid >> 6, lane = tid & 63;
    const int r    = lane & 15, gg = lane >> 4;

    // ---- P1 roles: block = (batch-quarter, 64-col tile); wave = (col-16, k-slice) ----
    const int p1_bq = g & 3, p1_cb = g >> 2;
    const int p1_ct = wv & 3, p1_ks = wv >> 2;
    // ---- P2 roles: block = (batch, col-quarter); 4 blocks/batch on same XCD ----
    const int p2_b  = (g & 7) * 8 + (g >> 5);
    const int p2_q4 = (g >> 3) & 3;
    // ---- P3 roles: block = (j-tile, batch-group) ----
    const int jt = g >> 2, bg = g & 3;
    const int j0 = jt * 16, b0 = bg * 16;
    const int lr = tid >> 4, lc = tid & 15;
    float hreg = (tid < 256) ? h0f[(long)(b0 + lr) * 1024 + j0 + lc] : 0.f;

    int ord = 0;

#pragma unroll 1
    for (int t = 0; t < T_; ++t) {
        // ======== P1: hp[64,4096] = h_{t-1} @ whp^T ; 16 rows x 64 cols per block ========
        {
            const int n0 = p1_cb * 64 + p1_ct * 16;
            const int k0 = p1_ks * 256;
            const int b  = p1_bq * 16 + r;
            const unsigned short* arow = (t == 0)
                ? hbf + (long)b * 1024 + k0 + gg * 8
                : preC + ((long)b * T_ + (t - 1)) * 4096 + 1024 + k0 + gg * 8;   // plain
            const unsigned short* bw = whp + (long)(n0 + r) * 1024 + k0 + gg * 8;
            f32x4 acc = {};
#pragma unroll
            for (int k = 0; k < 256; k += 32) {
                bf16x8 av = *(const bf16x8*)(arow + k);
                bf16x8 bv = *(const bf16x8*)(bw + k);
                acc = __builtin_amdgcn_mfma_f32_16x16x32_bf16(av, bv, acc, 0, 0, 0);
            }
            *(f32x4*)&smf[(wv * 64 + lane) * 4] = acc;
            __syncthreads();
            if (p1_ks == 0) {   // wv == p1_ct
                f32x4 s0 = *(f32x4*)&smf[((0 * 4 + p1_ct) * 64 + lane) * 4];
                f32x4 s1 = *(f32x4*)&smf[((1 * 4 + p1_ct) * 64 + lane) * 4];
                f32x4 s2 = *(f32x4*)&smf[((2 * 4 + p1_ct) * 64 + lane) * 4];
                f32x4 s3 = *(f32x4*)&smf[((3 * 4 + p1_ct) * 64 + lane) * 4];
                f32x4 s = s0 + s1 + s2 + s3;
#pragma unroll
                for (int rr = 0; rr < 4; ++rr)
                    st4f(&hp[(long)(p1_bq * 16 + gg * 4 + rr) * 4096 + n0 + r], s[rr]);
            }
        }
        gbar(sync, g, ++ord);

        // ======== P2: attention; 16B loads; ctx reduced in-wave ========
        {
            const int b = p2_b;
            // --- energy: wave = (h-half hq2, 16-score group sg); u16x8 pk loads ---
            const int hq2 = wv & 1, sg = wv >> 1;
            const int hh  = hq2 * 512 + lane * 8;
            float q[8], w8[8];
#pragma unroll
            for (int i = 0; i < 4; ++i) {
                unsigned long long u = ld8c(hp + (long)b * 4096 + hh + 2 * i);
                q[2 * i]     = __uint_as_float((unsigned)u);
                q[2 * i + 1] = __uint_as_float((unsigned)(u >> 32));
            }
#pragma unroll
            for (int i = 0; i < 8; ++i) w8[i] = We[hh + i];
            const unsigned short* pkb = pk + ((long)b * S_ + sg * 16) * 1024 + hh;
#pragma unroll 2
            for (int ss = 0; ss < 16; ++ss) {
                u16x8 pv = *(const u16x8*)(pkb + (long)ss * 1024);
                float acc = 0.f;
#pragma unroll
                for (int i = 0; i < 8; ++i) acc += my_tanh(q[i] + bf2f(pv[i])) * w8[i];
#pragma unroll
                for (int off = 32; off; off >>= 1) acc += __shfl_xor(acc, off);
                if (lane == 0) epart[hq2 * 128 + sg * 16 + ss] = acc;
            }
            __syncthreads();
            // --- softmax over 128 (threads 0..127) ---
            float e = 0.f, scv = 0.f;
            if (tid < 128) {
                scv = epart[tid] + epart[128 + tid];
                float m = scv;
#pragma unroll
                for (int off = 32; off; off >>= 1) m = fmaxf(m, __shfl_xor(m, off));
                if ((tid & 63) == 0) alr[128 + (tid >> 6)] = m;
            }
            __syncthreads();
            if (tid < 128) {
                float M = fmaxf(alr[128], alr[129]);
                e = __expf(scv - M);
                float s = e;
#pragma unroll
                for (int off = 32; off; off >>= 1) s += __shfl_xor(s, off);
                if ((tid & 63) == 0) alr[130 + (tid >> 6)] = s;
            }
            __syncthreads();
            if (tid < 128) alr[tid] = e / (alr[130] + alr[131]);
            __syncthreads();
            // --- context: thread = (col-group cg of 8 cols, s-range sr of 8 rows) ---
            // lane = (cg&3)*16 + sr  ->  shfl_xor over sr bits stays in-wave
            const int cg = tid >> 4, sr = tid & 15;
            const int col = p2_q4 * 512 + cg * 8;
            const unsigned short* ehp = eh + ((long)b * S_ + sr * 8) * 2048 + col;
            float c8[8] = {};
#pragma unroll
            for (int i = 0; i < 8; ++i) {
                float alv = alr[sr * 8 + i];
                u16x8 ev = *(const u16x8*)(ehp + (long)i * 2048);
#pragma unroll
                for (int j = 0; j < 8; ++j) c8[j] += alv * bf2f(ev[j]);
            }
#pragma unroll
            for (int off = 1; off < 16; off <<= 1) {
#pragma unroll
                for (int j = 0; j < 8; ++j) c8[j] += __shfl_xor(c8[j], off);
            }
            if (sr == 0) {
                unsigned short* dst = preC + ((long)b * T_ + t) * 4096 + 2048 + col;
                unsigned long long v0 =
                      (unsigned long long)f2bf(c8[0])
                    | ((unsigned long long)f2bf(c8[1]) << 16)
                    | ((unsigned long long)f2bf(c8[2]) << 32)
                    | ((unsigned long long)f2bf(c8[3]) << 48);
                unsigned long long v1 =
                      (unsigned long long)f2bf(c8[4])
                    | ((unsigned long long)f2bf(c8[5]) << 16)
                    | ((unsigned long long)f2bf(c8[6]) << 32)
                    | ((unsigned long long)f2bf(c8[7]) << 48);
                st8c(dst, v0);
                st8c(dst + 4, v1);
            }
        }
        gbar(sync, g, ++ord);

        // ======== P3: gi_ctx MFMA + GRU gates; wave = (gate, k-slice of 512) ========
        {
            if (wv < 12) {
                const int c = wv >> 2, ks = wv & 3, k0 = ks * 512;
                const unsigned short* ar = preC + ((long)(b0 + r) * T_ + t) * 4096 + 2048 + k0 + gg * 8; // plain
                const unsigned short* bw = wih + ((long)(c * 1024 + j0 + r)) * 3072 + 1024 + k0 + gg * 8;
                f32x4 acc = {};
#pragma unroll
                for (int k = 0; k < 512; k += 32) {
                    bf16x8 av = *(const bf16x8*)(ar + k);
                    bf16x8 bv = *(const bf16x8*)(bw + k);
                    acc = __builtin_amdgcn_mfma_f32_16x16x32_bf16(av, bv, acc, 0, 0, 0);
                }
                *(f32x4*)&smf[(wv * 64 + lane) * 4] = acc;
            }
            __syncthreads();
            if (tid < 256) {
                const int lane_ = (lr >> 2) * 16 + lc, rr_ = lr & 3;
                float gi[3];
#pragma unroll
                for (int c = 0; c < 3; ++c) {
                    gi[c] = smf[((c * 4 + 0) * 64 + lane_) * 4 + rr_]
                          + smf[((c * 4 + 1) * 64 + lane_) * 4 + rr_]
                          + smf[((c * 4 + 2) * 64 + lane_) * 4 + rr_]
                          + smf[((c * 4 + 3) * 64 + lane_) * 4 + rr_];
                }
                const int b = b0 + lr, j = j0 + lc;
                const long bt = (long)b * T_ + t;
                float ghr = ld4f(&hp[(long)b * 4096 + 1024 + j]);
                float ghz = ld4f(&hp[(long)b * 4096 + 2048 + j]);
                float ghn = ld4f(&hp[(long)b * 4096 + 3072 + j]);
                float grv = gix[bt * 3072 + j]        + gi[0] + bih[j]        + ghr + bhh[j];
                float gzv = gix[bt * 3072 + 1024 + j] + gi[1] + bih[1024 + j] + ghz + bhh[1024 + j];
                float gni = gix[bt * 3072 + 2048 + j] + gi[2] + bih[2048 + j];
                float ghn2 = ghn + bhh[2048 + j];
                float rg = my_sig(grv);
                float zg = my_sig(gzv);
                float nv = my_tanh(gni + rg * ghn2);
                float hn = (1.f - zg) * nv + zg * hreg;
                hreg = hn;
                unsigned short hb16 = f2bf(hn);
                o_states[bt * 1024 + j] = hn;                    // plain (read after kernel)
                if (t == T_ - 1) o_hf[(long)b * 1024 + j] = hn;  // plain
                hsm[tid] = hb16;
            }
            __syncthreads();
            // pack h_t -> preC h-slot (sc1; next-step P1 reads plain)
            if (tid < 64) {
                const int plr = tid >> 2, pc4 = (tid & 3) * 4;
                unsigned long long v =
                      (unsigned long long)hsm[plr * 16 + pc4]
                    | ((unsigned long long)hsm[plr * 16 + pc4 + 1] << 16)
                    | ((unsigned long long)hsm[plr * 16 + pc4 + 2] << 32)
                    | ((unsigned long long)hsm[plr * 16 + pc4 + 3] << 48);
                st8c(preC + ((long)(b0 + plr) * T_ + t) * 4096 + 1024 + j0 + pc4, v);
            }
        }
        gbar(sync, g, ++ord);
    }
}

// ---------- host ----------
extern "C" void kernel_launch(void* const* d_in, const int* in_sizes, int n_in,
                              void* d_out, int out_size, void* d_ws, size_t ws_size,
                              hipStream_t stream) {
    const float* te  = (const float*)d_in[0];
    const float* eh  = (const float*)d_in[1];
    const float* ef  = (const float*)d_in[2];
    const float* Wb  = (const float*)d_in[5];
    const float* bb  = (const float*)d_in[6];
    const float* Wk  = (const float*)d_in[7];
    const float* Wq  = (const float*)d_in[8];
    const float* We  = (const float*)d_in[9];
    const float* Wih = (const float*)d_in[10];
    const float* Whh = (const float*)d_in[11];
    const float* bih = (const float*)d_in[12];
    const float* bhh = (const float*)d_in[13];
    const float* Wpre= (const float*)d_in[14];

    char* ws = (char*)d_ws;
    if (ws_size < 272236544UL) return;   // loud failure (output stays poisoned)
    float*          h0f   = (float*)(ws + 0);                  // 64*1024*4
    float*          hp    = (float*)(ws + 262144);             // 64*4096*4
    unsigned short* hbf   = (unsigned short*)(ws + 1310720);   // 64*1024*2 (h0 only)
    unsigned short* efb   = (unsigned short*)(ws + 1441792);   // 64*2048*2 (init only)
    int*            syncb = (int*)(ws + 1441792 + 65536);      // barrier vars (aliases efb tail)
    unsigned short* ehb   = (unsigned short*)(ws + 1703936);   // B*S*2048*2
    unsigned short* pkb   = (unsigned short*)(ws + 35258368);  // B*S*1024*2
    unsigned short* preC  = (unsigned short*)(ws + 52035584);  // B*T*4096*2
    float*          gix   = (float*)(ws + 119144448);          // B*T*3072*4
    unsigned short* wbb   = (unsigned short*)(ws + 219807744); // 1024*2048*2
    unsigned short* wkb   = (unsigned short*)(ws + 224002048); // 1024*2048*2
    unsigned short* whpb  = (unsigned short*)(ws + 228196352); // 4096*1024*2
    unsigned short* wihb  = (unsigned short*)(ws + 236584960); // 3072*3072*2
    unsigned short* wpreb = (unsigned short*)(ws + 255459328); // 2048*4096*2

    float* o_states = (float*)d_out;                 // (B,T,H)
    float* o_hf     = o_states + (long)B_ * T_ * H_; // (1,B,H)
    float* o_pre    = o_hf + (long)B_ * H_;          // (B,T,2H)

    auto cvt = [&](const float* s, unsigned short* d, long n) {
        k_cvt<<<dim3((unsigned)((n / 4 + 255) / 256)), 256, 0, stream>>>(s, d, n);
    };
    cvt(eh,  ehb,  (long)B_ * S_ * 2048);
    cvt(ef,  efb,  (long)B_ * 2048);
    cvt(Wb,  wbb,  1024L * 2048);
    cvt(Wk,  wkb,  1024L * 2048);
    cvt(Wq,  whpb, 1024L * 1024);
    cvt(Whh, whpb + 1024L * 1024, 3072L * 1024);
    cvt(Wih, wihb, 3072L * 3072);
    cvt(Wpre,wpreb,2048L * 4096);
    k_cvt_te<<<8192, 256, 0, stream>>>(te, preC, (long)B_ * T_ * 1024);

    // h0 = tanh(encoder_final @ W_bridge^T + b_bridge)  (consumes efb)
    k_gemm<0><<<dim3(16, 1), 256, 0, stream>>>(efb, 2048, wbb, 2048, hp, 1024, 2048);
    k_h0act<<<256, 256, 0, stream>>>(hp, bb, h0f, hbf);
    // reset barrier vars (stream-ordered, deterministic per call)
    (void)hipMemsetAsync(syncb, 0, 16384, stream);
    // proj_key = encoder_hidden @ W_key^T  (bf16 out)
    k_gemm<1><<<dim3(16, 128), 256, 0, stream>>>(ehb, 2048, wkb, 2048, pkb, 1024, 2048);
    // gi_x = trg_embed @ W_ih[:, :E]^T  (f32 out)
    k_gemm<0><<<dim3(48, 128), 256, 0, stream>>>(preC, 4096, wihb, 3072, gix, 3072, 1024);

    // persistent step loop: 256 blocks x 1024 threads
    k_steps<<<NBLK, 1024, 0, stream>>>(pkb, ehb, whpb, wihb, We, gix, bih, bhh,
                                       h0f, hbf, hp, preC, o_states, o_hf, syncb);

    // pre_output = [x_t, h_t, ctx_t] @ W_pre^T
    k_gemm<0><<<dim3(32, 128), 256, 0, stream>>>(preC, 4096, wpreb, 4096, o_pre, 2048, 4096);
}

// Round 11
// 8176.301 us; speedup vs baseline: 1.1691x; 1.1691x over previous
//
#include <hip/hip_runtime.h>
#include <hip/hip_bf16.h>

// ---------- types ----------
typedef short    bf16x8 __attribute__((ext_vector_type(8)));   // 8 bf16 (4 VGPRs), MFMA A/B frag
typedef float    f32x4  __attribute__((ext_vector_type(4)));   // MFMA C/D frag
typedef unsigned short u16x8 __attribute__((ext_vector_type(8)));

#define B_  64
#define S_  128
#define T_  128
#define E_  1024
#define H_  1024
#define NBLK 256

#define RLX __ATOMIC_RELAXED
#define AGT __HIP_MEMORY_SCOPE_AGENT

__device__ __forceinline__ unsigned short f2bf(float f) {
    unsigned u = __float_as_uint(f);
    unsigned r = (u + 0x7FFFu + ((u >> 16) & 1u)) >> 16;   // RNE
    return (unsigned short)r;
}
__device__ __forceinline__ float bf2f(unsigned short u) {
    return __uint_as_float((unsigned)u << 16);
}
__device__ __forceinline__ float my_tanh(float x) {
    float e = __expf(2.0f * x);
    return 1.0f - 2.0f / (e + 1.0f);
}
__device__ __forceinline__ float my_sig(float x) {
    return 1.0f / (1.0f + __expf(-x));
}

// ---------- coherent (L2-bypass) relaxed accessors ----------
__device__ __forceinline__ void st8c(void* p, unsigned long long v) {
    __hip_atomic_store((unsigned long long*)p, v, RLX, AGT);
}
__device__ __forceinline__ unsigned long long ld8c(const void* p) {
    return __hip_atomic_load((const unsigned long long*)p, RLX, AGT);
}
__device__ __forceinline__ void st4c(void* p, unsigned v) {
    __hip_atomic_store((unsigned*)p, v, RLX, AGT);
}
__device__ __forceinline__ void st4f(void* p, float v) {
    __hip_atomic_store((float*)p, v, RLX, AGT);
}
__device__ __forceinline__ float ld4f(const void* p) {
    return __hip_atomic_load((const float*)p, RLX, AGT);
}

// ---------- 2-level grid barrier: 32 leaves x 8, relaxed atomics only ----------
__device__ __forceinline__ void gbar(int* sync, int g, int ord) {
    __syncthreads();                         // drains vmcnt -> sc1 stores at coherence point
    if (threadIdx.x == 0) {
        int* lc = sync + 64 + (g >> 3) * 64;
        int* lg = lc + 32;
        if (__hip_atomic_fetch_add(lc, 1, RLX, AGT) == 8 * ord - 1) {
            if (__hip_atomic_fetch_add(sync, 1, RLX, AGT) == 32 * ord - 1) {
                __hip_atomic_store(sync + 32, ord, RLX, AGT);
            } else {
                while (__hip_atomic_load(sync + 32, RLX, AGT) < ord)
                    __builtin_amdgcn_s_sleep(2);
            }
            __hip_atomic_store(lg, ord, RLX, AGT);
        } else {
            while (__hip_atomic_load(lg, RLX, AGT) < ord)
                __builtin_amdgcn_s_sleep(2);
        }
    }
    __syncthreads();
}

// ---------- f32 -> bf16 conversion ----------
__global__ void k_cvt(const float* __restrict__ s, unsigned short* __restrict__ d, long n) {
    long i = ((long)blockIdx.x * blockDim.x + threadIdx.x) * 4;
    if (i >= n) return;
    float4 f = *(const float4*)(s + i);
    ushort4 o;
    o.x = f2bf(f.x); o.y = f2bf(f.y); o.z = f2bf(f.z); o.w = f2bf(f.w);
    *(ushort4*)(d + i) = o;
}

// trg_embed (B,T,1024) -> preC[(b*T+t)*4096 + 0..1023]
__global__ void k_cvt_te(const float* __restrict__ s, unsigned short* __restrict__ d, long n) {
    long i = ((long)blockIdx.x * blockDim.x + threadIdx.x) * 4;
    if (i >= n) return;
    float4 f = *(const float4*)(s + i);
    long row = i >> 10, col = i & 1023;
    ushort4 o;
    o.x = f2bf(f.x); o.y = f2bf(f.y); o.z = f2bf(f.z); o.w = f2bf(f.w);
    *(ushort4*)(d + row * 4096 + col) = o;
}

// ---------- generic MFMA GEMM: C[M,N] = A[M,K] @ W[N,K]^T ----------
template<int OUTBF>
__global__ __launch_bounds__(256) void k_gemm(const unsigned short* __restrict__ A, long lda,
                                              const unsigned short* __restrict__ W, long ldw,
                                              void* __restrict__ Cv, long ldc, int K) {
    const int lane = threadIdx.x & 63;
    const int wv   = threadIdx.x >> 6;
    const int r    = lane & 15, g = lane >> 4;
    const long m0  = (long)blockIdx.y * 64 + wv * 16;
    const long n0  = (long)blockIdx.x * 64;
    const unsigned short* a  = A + (m0 + r) * lda + g * 8;
    const unsigned short* w0 = W + (n0 + r) * ldw + g * 8;
    f32x4 acc[4] = {};
    for (int k = 0; k < K; k += 32) {
        bf16x8 av = *(const bf16x8*)(a + k);
#pragma unroll
        for (int j = 0; j < 4; ++j) {
            bf16x8 bv = *(const bf16x8*)(w0 + (long)j * 16 * ldw + k);
            acc[j] = __builtin_amdgcn_mfma_f32_16x16x32_bf16(av, bv, acc[j], 0, 0, 0);
        }
    }
#pragma unroll
    for (int j = 0; j < 4; ++j) {
        long row = m0 + g * 4;
        long col = n0 + j * 16 + r;
#pragma unroll
        for (int rr = 0; rr < 4; ++rr) {
            float v = acc[j][rr];
            if (OUTBF) ((unsigned short*)Cv)[(row + rr) * ldc + col] = f2bf(v);
            else       ((float*)Cv)[(row + rr) * ldc + col] = v;
        }
    }
}

// ---------- h0 activation ----------
__global__ void k_h0act(const float* __restrict__ hp, const float* __restrict__ bb,
                        float* __restrict__ h, unsigned short* __restrict__ hbf) {
    int i = blockIdx.x * 256 + threadIdx.x;   // 65536
    float v = my_tanh(hp[i] + bb[i & 1023]);
    h[i] = v; hbf[i] = f2bf(v);
}

// ---------- persistent step loop: 256 blocks x 1024 thr, 3 barriers/step ----------
// Round-6 structure + eh slice (128 KB per block) pinned in LDS for the whole kernel.
__global__ __launch_bounds__(1024) void k_steps(
        const unsigned short* __restrict__ pk, const unsigned short* __restrict__ eh,
        const unsigned short* __restrict__ whp, const unsigned short* __restrict__ wih,
        const float* __restrict__ We, const float* __restrict__ gix,
        const float* __restrict__ bih, const float* __restrict__ bhh,
        const float* __restrict__ h0f, const unsigned short* __restrict__ hbf,
        float* __restrict__ hp, unsigned short* __restrict__ preC,
        float* __restrict__ o_states, float* __restrict__ o_hf,
        int* __restrict__ sync) {
    __shared__ unsigned short ehs[S_ * 512];  // 128 KB: eh[p2_b][:, q4*512 .. +512) resident
    __shared__ float smf[16 * 64 * 4];        // 16 KB, reused per phase
    __shared__ unsigned short hsm[256];
    const int g    = blockIdx.x;
    const int tid  = threadIdx.x;
    const int wv   = tid >> 6, lane = tid & 63;
    const int r    = lane & 15, gg = lane >> 4;

    // ---- P1 roles: block = (batch-quarter, 64-col tile); wave = (col-16, k-slice) ----
    const int p1_bq = g & 3, p1_cb = g >> 2;
    const int p1_ct = wv & 3, p1_ks = wv >> 2;
    // ---- P2 roles: block = (batch, col-quarter); 4 blocks/batch on same XCD ----
    const int p2_b  = (g & 7) * 8 + (g >> 5);
    const int p2_q4 = (g >> 3) & 3;
    // ---- P3 roles: block = (j-tile, batch-group) ----
    const int jt = g >> 2, bg = g & 3;
    const int j0 = jt * 16, b0 = bg * 16;
    const int lr = tid >> 4, lc = tid & 15;
    float hreg = (tid < 256) ? h0f[(long)(b0 + lr) * 1024 + j0 + lc] : 0.f;

    // ---- one-time: stage this block's eh slice into LDS (128 rows x 512 cols bf16) ----
    {
        const unsigned short* src = eh + (long)p2_b * S_ * 2048 + p2_q4 * 512;
#pragma unroll
        for (int it = 0; it < 8; ++it) {
            int i = it * 1024 + tid;              // 8192 chunks of 8 ushorts
            int row = i >> 6, c8i = (i & 63) * 8;
            *(u16x8*)&ehs[row * 512 + c8i] = *(const u16x8*)(src + (long)row * 2048 + c8i);
        }
    }
    __syncthreads();

    int ord = 0;

#pragma unroll 1
    for (int t = 0; t < T_; ++t) {
        // ======== P1: hp[64,4096] = h_{t-1} @ whp^T ; 16 rows x 64 cols per block ========
        {
            const int n0 = p1_cb * 64 + p1_ct * 16;
            const int k0 = p1_ks * 256;
            const int b  = p1_bq * 16 + r;
            const unsigned short* arow = (t == 0)
                ? hbf + (long)b * 1024 + k0 + gg * 8
                : preC + ((long)b * T_ + (t - 1)) * 4096 + 1024 + k0 + gg * 8;   // plain
            const unsigned short* bw = whp + (long)(n0 + r) * 1024 + k0 + gg * 8;
            f32x4 acc = {};
#pragma unroll
            for (int k = 0; k < 256; k += 32) {
                bf16x8 av = *(const bf16x8*)(arow + k);
                bf16x8 bv = *(const bf16x8*)(bw + k);
                acc = __builtin_amdgcn_mfma_f32_16x16x32_bf16(av, bv, acc, 0, 0, 0);
            }
            *(f32x4*)&smf[(wv * 64 + lane) * 4] = acc;
            __syncthreads();
            if (p1_ks == 0) {   // wv == p1_ct
                f32x4 s0 = *(f32x4*)&smf[((0 * 4 + p1_ct) * 64 + lane) * 4];
                f32x4 s1 = *(f32x4*)&smf[((1 * 4 + p1_ct) * 64 + lane) * 4];
                f32x4 s2 = *(f32x4*)&smf[((2 * 4 + p1_ct) * 64 + lane) * 4];
                f32x4 s3 = *(f32x4*)&smf[((3 * 4 + p1_ct) * 64 + lane) * 4];
                f32x4 s = s0 + s1 + s2 + s3;
#pragma unroll
                for (int rr = 0; rr < 4; ++rr)
                    st4f(&hp[(long)(p1_bq * 16 + gg * 4 + rr) * 4096 + n0 + r], s[rr]);
            }
        }
        gbar(sync, g, ++ord);

        // ======== P2: attention for batch p2_b; ctx sourced from LDS-resident eh ========
        {
            const int b = p2_b;
            // energy: wave = (h-quarter hq, score-group sg); lane covers 4 h-elems
            const int hq = wv & 3, sg = wv >> 2;
            const int hh = hq * 256 + lane * 4;
            float q0, q1, q2, q3;
            {
                unsigned long long u0 = ld8c(hp + (long)b * 4096 + hh);
                unsigned long long u1 = ld8c(hp + (long)b * 4096 + hh + 2);
                q0 = __uint_as_float((unsigned)u0); q1 = __uint_as_float((unsigned)(u0 >> 32));
                q2 = __uint_as_float((unsigned)u1); q3 = __uint_as_float((unsigned)(u1 >> 32));
            }
            const float w0 = We[hh], w1 = We[hh + 1], w2 = We[hh + 2], w3 = We[hh + 3];
            const unsigned short* pkb = pk + ((long)b * S_ + sg * 32) * 1024 + hh;
#pragma unroll 2
            for (int ss = 0; ss < 32; ++ss) {
                ushort4 pv = *(const ushort4*)(pkb + (long)ss * 1024);
                float acc = my_tanh(q0 + bf2f(pv.x)) * w0
                          + my_tanh(q1 + bf2f(pv.y)) * w1
                          + my_tanh(q2 + bf2f(pv.z)) * w2
                          + my_tanh(q3 + bf2f(pv.w)) * w3;
#pragma unroll
                for (int off = 32; off; off >>= 1) acc += __shfl_xor(acc, off);
                if (lane == 0) smf[hq * 128 + sg * 32 + ss] = acc;   // epart[hq][s]
            }
            __syncthreads();
            float* red = &smf[648];
            float e = 0.f, sc = 0.f;
            if (tid < 128) {
                sc = smf[tid] + smf[128 + tid] + smf[256 + tid] + smf[384 + tid];
                float m = sc;
#pragma unroll
                for (int off = 32; off; off >>= 1) m = fmaxf(m, __shfl_xor(m, off));
                if ((tid & 63) == 0) red[tid >> 6] = m;
            }
            __syncthreads();
            if (tid < 128) {
                float M = fmaxf(red[0], red[1]);
                e = __expf(sc - M);
                float s = e;
#pragma unroll
                for (int off = 32; off; off >>= 1) s += __shfl_xor(s, off);
                if ((tid & 63) == 0) red[2 + (tid >> 6)] = s;
            }
            __syncthreads();
            if (tid < 128) smf[512 + tid] = e / (red[2] + red[3]);
            __syncthreads();
            // context: thread = (col-pair cp, s-segment sseg of 32); LDS source
            const int cp = tid & 255, sseg = tid >> 8;
            const unsigned short* ehp = ehs + (sseg * 32) * 512 + cp * 2;
            float a0 = 0.f, a1 = 0.f;
#pragma unroll 4
            for (int s2 = 0; s2 < 32; ++s2) {
                float alv = smf[512 + sseg * 32 + s2];
                ushort2 v = *(const ushort2*)(ehp + s2 * 512);
                a0 += alv * bf2f(v.x); a1 += alv * bf2f(v.y);
            }
            smf[1024 + (sseg * 256 + cp) * 2]     = a0;
            smf[1024 + (sseg * 256 + cp) * 2 + 1] = a1;
            __syncthreads();
            if (tid < 256) {
                float b0s = smf[1024 + tid * 2]         + smf[1024 + (256 + tid) * 2]
                          + smf[1024 + (512 + tid) * 2] + smf[1024 + (768 + tid) * 2];
                float b1s = smf[1024 + tid * 2 + 1]         + smf[1024 + (256 + tid) * 2 + 1]
                          + smf[1024 + (512 + tid) * 2 + 1] + smf[1024 + (768 + tid) * 2 + 1];
                unsigned pack = (unsigned)f2bf(b0s) | ((unsigned)f2bf(b1s) << 16);
                st4c(preC + ((long)b * T_ + t) * 4096 + 2048 + p2_q4 * 512 + tid * 2, pack);
            }
        }
        gbar(sync, g, ++ord);

        // ======== P3: gi_ctx MFMA + GRU gates; wave = (gate, k-slice of 512) ========
        {
            if (wv < 12) {
                const int c = wv >> 2, ks = wv & 3, k0 = ks * 512;
                const unsigned short* ar = preC + ((long)(b0 + r) * T_ + t) * 4096 + 2048 + k0 + gg * 8; // plain
                const unsigned short* bw = wih + ((long)(c * 1024 + j0 + r)) * 3072 + 1024 + k0 + gg * 8;
                f32x4 acc = {};
#pragma unroll
                for (int k = 0; k < 512; k += 32) {
                    bf16x8 av = *(const bf16x8*)(ar + k);
                    bf16x8 bv = *(const bf16x8*)(bw + k);
                    acc = __builtin_amdgcn_mfma_f32_16x16x32_bf16(av, bv, acc, 0, 0, 0);
                }
                *(f32x4*)&smf[(wv * 64 + lane) * 4] = acc;
            }
            __syncthreads();
            if (tid < 256) {
                const int lane_ = (lr >> 2) * 16 + lc, rr_ = lr & 3;
                float gi[3];
#pragma unroll
                for (int c = 0; c < 3; ++c) {
                    gi[c] = smf[((c * 4 + 0) * 64 + lane_) * 4 + rr_]
                          + smf[((c * 4 + 1) * 64 + lane_) * 4 + rr_]
                          + smf[((c * 4 + 2) * 64 + lane_) * 4 + rr_]
                          + smf[((c * 4 + 3) * 64 + lane_) * 4 + rr_];
                }
                const int b = b0 + lr, j = j0 + lc;
                const long bt = (long)b * T_ + t;
                float ghr = ld4f(&hp[(long)b * 4096 + 1024 + j]);
                float ghz = ld4f(&hp[(long)b * 4096 + 2048 + j]);
                float ghn = ld4f(&hp[(long)b * 4096 + 3072 + j]);
                float grv = gix[bt * 3072 + j]        + gi[0] + bih[j]        + ghr + bhh[j];
                float gzv = gix[bt * 3072 + 1024 + j] + gi[1] + bih[1024 + j] + ghz + bhh[1024 + j];
                float gni = gix[bt * 3072 + 2048 + j] + gi[2] + bih[2048 + j];
                float ghn2 = ghn + bhh[2048 + j];
                float rg = my_sig(grv);
                float zg = my_sig(gzv);
                float nv = my_tanh(gni + rg * ghn2);
                float hn = (1.f - zg) * nv + zg * hreg;
                hreg = hn;
                unsigned short hb16 = f2bf(hn);
                o_states[bt * 1024 + j] = hn;                    // plain (read after kernel)
                if (t == T_ - 1) o_hf[(long)b * 1024 + j] = hn;  // plain
                hsm[tid] = hb16;
            }
            __syncthreads();
            // pack h_t -> preC h-slot (sc1; next-step P1 reads plain)
            if (tid < 64) {
                const int plr = tid >> 2, pc4 = (tid & 3) * 4;
                unsigned long long v =
                      (unsigned long long)hsm[plr * 16 + pc4]
                    | ((unsigned long long)hsm[plr * 16 + pc4 + 1] << 16)
                    | ((unsigned long long)hsm[plr * 16 + pc4 + 2] << 32)
                    | ((unsigned long long)hsm[plr * 16 + pc4 + 3] << 48);
                st8c(preC + ((long)(b0 + plr) * T_ + t) * 4096 + 1024 + j0 + pc4, v);
            }
        }
        gbar(sync, g, ++ord);
    }
}

// ---------- host ----------
extern "C" void kernel_launch(void* const* d_in, const int* in_sizes, int n_in,
                              void* d_out, int out_size, void* d_ws, size_t ws_size,
                              hipStream_t stream) {
    const float* te  = (const float*)d_in[0];
    const float* eh  = (const float*)d_in[1];
    const float* ef  = (const float*)d_in[2];
    const float* Wb  = (const float*)d_in[5];
    const float* bb  = (const float*)d_in[6];
    const float* Wk  = (const float*)d_in[7];
    const float* Wq  = (const float*)d_in[8];
    const float* We  = (const float*)d_in[9];
    const float* Wih = (const float*)d_in[10];
    const float* Whh = (const float*)d_in[11];
    const float* bih = (const float*)d_in[12];
    const float* bhh = (const float*)d_in[13];
    const float* Wpre= (const float*)d_in[14];

    char* ws = (char*)d_ws;
    if (ws_size < 272236544UL) return;   // loud failure (output stays poisoned)
    float*          h0f   = (float*)(ws + 0);                  // 64*1024*4
    float*          hp    = (float*)(ws + 262144);             // 64*4096*4
    unsigned short* hbf   = (unsigned short*)(ws + 1310720);   // 64*1024*2 (h0 only)
    unsigned short* efb   = (unsigned short*)(ws + 1441792);   // 64*2048*2 (init only)
    int*            syncb = (int*)(ws + 1441792 + 65536);      // barrier vars (aliases efb tail)
    unsigned short* ehb   = (unsigned short*)(ws + 1703936);   // B*S*2048*2
    unsigned short* pkb   = (unsigned short*)(ws + 35258368);  // B*S*1024*2
    unsigned short* preC  = (unsigned short*)(ws + 52035584);  // B*T*4096*2
    float*          gix   = (float*)(ws + 119144448);          // B*T*3072*4
    unsigned short* wbb   = (unsigned short*)(ws + 219807744); // 1024*2048*2
    unsigned short* wkb   = (unsigned short*)(ws + 224002048); // 1024*2048*2
    unsigned short* whpb  = (unsigned short*)(ws + 228196352); // 4096*1024*2
    unsigned short* wihb  = (unsigned short*)(ws + 236584960); // 3072*3072*2
    unsigned short* wpreb = (unsigned short*)(ws + 255459328); // 2048*4096*2

    float* o_states = (float*)d_out;                 // (B,T,H)
    float* o_hf     = o_states + (long)B_ * T_ * H_; // (1,B,H)
    float* o_pre    = o_hf + (long)B_ * H_;          // (B,T,2H)

    auto cvt = [&](const float* s, unsigned short* d, long n) {
        k_cvt<<<dim3((unsigned)((n / 4 + 255) / 256)), 256, 0, stream>>>(s, d, n);
    };
    cvt(eh,  ehb,  (long)B_ * S_ * 2048);
    cvt(ef,  efb,  (long)B_ * 2048);
    cvt(Wb,  wbb,  1024L * 2048);
    cvt(Wk,  wkb,  1024L * 2048);
    cvt(Wq,  whpb, 1024L * 1024);
    cvt(Whh, whpb + 1024L * 1024, 3072L * 1024);
    cvt(Wih, wihb, 3072L * 3072);
    cvt(Wpre,wpreb,2048L * 4096);
    k_cvt_te<<<8192, 256, 0, stream>>>(te, preC, (long)B_ * T_ * 1024);

    // h0 = tanh(encoder_final @ W_bridge^T + b_bridge)  (consumes efb)
    k_gemm<0><<<dim3(16, 1), 256, 0, stream>>>(efb, 2048, wbb, 2048, hp, 1024, 2048);
    k_h0act<<<256, 256, 0, stream>>>(hp, bb, h0f, hbf);
    // reset barrier vars (stream-ordered, deterministic per call)
    (void)hipMemsetAsync(syncb, 0, 16384, stream);
    // proj_key = encoder_hidden @ W_key^T  (bf16 out)
    k_gemm<1><<<dim3(16, 128), 256, 0, stream>>>(ehb, 2048, wkb, 2048, pkb, 1024, 2048);
    // gi_x = trg_embed @ W_ih[:, :E]^T  (f32 out)
    k_gemm<0><<<dim3(48, 128), 256, 0, stream>>>(preC, 4096, wihb, 3072, gix, 3072, 1024);

    // persistent step loop: 256 blocks x 1024 threads, eh pinned in LDS
    k_steps<<<NBLK, 1024, 0, stream>>>(pkb, ehb, whpb, wihb, We, gix, bih, bhh,
                                       h0f, hbf, hp, preC, o_states, o_hf, syncb);

    // pre_output = [x_t, h_t, ctx_t] @ W_pre^T
    k_gemm<0><<<dim3(32, 128), 256, 0, stream>>>(preC, 4096, wpreb, 4096, o_pre, 2048, 4096);
}

// Round 12
// 6959.933 us; speedup vs baseline: 1.3734x; 1.1748x over previous
//
#include <hip/hip_runtime.h>
#include <hip/hip_bf16.h>

// ---------- types ----------
typedef short    bf16x8 __attribute__((ext_vector_type(8)));   // 8 bf16 (4 VGPRs), MFMA A/B frag
typedef float    f32x4  __attribute__((ext_vector_type(4)));   // MFMA C/D frag
typedef unsigned short u16x8 __attribute__((ext_vector_type(8)));

#define B_  64
#define S_  128
#define T_  128
#define E_  1024
#define H_  1024
#define NBLK 256

#define RLX __ATOMIC_RELAXED
#define AGT __HIP_MEMORY_SCOPE_AGENT

__device__ __forceinline__ unsigned short f2bf(float f) {
    unsigned u = __float_as_uint(f);
    unsigned r = (u + 0x7FFFu + ((u >> 16) & 1u)) >> 16;   // RNE
    return (unsigned short)r;
}
__device__ __forceinline__ float bf2f(unsigned short u) {
    return __uint_as_float((unsigned)u << 16);
}
__device__ __forceinline__ float my_tanh(float x) {
    float e = __expf(2.0f * x);
    return 1.0f - 2.0f / (e + 1.0f);
}
__device__ __forceinline__ float my_sig(float x) {
    return 1.0f / (1.0f + __expf(-x));
}

// ---------- coherent (L2-bypass) relaxed accessors ----------
__device__ __forceinline__ void st8c(void* p, unsigned long long v) {
    __hip_atomic_store((unsigned long long*)p, v, RLX, AGT);
}
__device__ __forceinline__ unsigned long long ld8c(const void* p) {
    return __hip_atomic_load((const unsigned long long*)p, RLX, AGT);
}
__device__ __forceinline__ void st4c(void* p, unsigned v) {
    __hip_atomic_store((unsigned*)p, v, RLX, AGT);
}
__device__ __forceinline__ void st4f(void* p, float v) {
    __hip_atomic_store((float*)p, v, RLX, AGT);
}
__device__ __forceinline__ float ld4f(const void* p) {
    return __hip_atomic_load((const float*)p, RLX, AGT);
}

// ---------- 2-level grid barrier: 32 leaves x 8, relaxed atomics only ----------
__device__ __forceinline__ void gbar(int* sync, int g, int ord) {
    __syncthreads();                         // drains vmcnt -> sc1 stores at coherence point
    if (threadIdx.x == 0) {
        int* lc = sync + 64 + (g >> 3) * 64;
        int* lg = lc + 32;
        if (__hip_atomic_fetch_add(lc, 1, RLX, AGT) == 8 * ord - 1) {
            if (__hip_atomic_fetch_add(sync, 1, RLX, AGT) == 32 * ord - 1) {
                __hip_atomic_store(sync + 32, ord, RLX, AGT);
            } else {
                while (__hip_atomic_load(sync + 32, RLX, AGT) < ord)
                    __builtin_amdgcn_s_sleep(2);
            }
            __hip_atomic_store(lg, ord, RLX, AGT);
        } else {
            while (__hip_atomic_load(lg, RLX, AGT) < ord)
                __builtin_amdgcn_s_sleep(2);
        }
    }
    __syncthreads();
}

// ---------- f32 -> bf16 conversion ----------
__global__ void k_cvt(const float* __restrict__ s, unsigned short* __restrict__ d, long n) {
    long i = ((long)blockIdx.x * blockDim.x + threadIdx.x) * 4;
    if (i >= n) return;
    float4 f = *(const float4*)(s + i);
    ushort4 o;
    o.x = f2bf(f.x); o.y = f2bf(f.y); o.z = f2bf(f.z); o.w = f2bf(f.w);
    *(ushort4*)(d + i) = o;
}

// trg_embed (B,T,1024) -> preC[(b*T+t)*4096 + 0..1023]
__global__ void k_cvt_te(const float* __restrict__ s, unsigned short* __restrict__ d, long n) {
    long i = ((long)blockIdx.x * blockDim.x + threadIdx.x) * 4;
    if (i >= n) return;
    float4 f = *(const float4*)(s + i);
    long row = i >> 10, col = i & 1023;
    ushort4 o;
    o.x = f2bf(f.x); o.y = f2bf(f.y); o.z = f2bf(f.z); o.w = f2bf(f.w);
    *(ushort4*)(d + row * 4096 + col) = o;
}

// ---------- generic MFMA GEMM: C[M,N] = A[M,K] @ W[N,K]^T ----------
template<int OUTBF>
__global__ __launch_bounds__(256) void k_gemm(const unsigned short* __restrict__ A, long lda,
                                              const unsigned short* __restrict__ W, long ldw,
                                              void* __restrict__ Cv, long ldc, int K) {
    const int lane = threadIdx.x & 63;
    const int wv   = threadIdx.x >> 6;
    const int r    = lane & 15, g = lane >> 4;
    const long m0  = (long)blockIdx.y * 64 + wv * 16;
    const long n0  = (long)blockIdx.x * 64;
    const unsigned short* a  = A + (m0 + r) * lda + g * 8;
    const unsigned short* w0 = W + (n0 + r) * ldw + g * 8;
    f32x4 acc[4] = {};
    for (int k = 0; k < K; k += 32) {
        bf16x8 av = *(const bf16x8*)(a + k);
#pragma unroll
        for (int j = 0; j < 4; ++j) {
            bf16x8 bv = *(const bf16x8*)(w0 + (long)j * 16 * ldw + k);
            acc[j] = __builtin_amdgcn_mfma_f32_16x16x32_bf16(av, bv, acc[j], 0, 0, 0);
        }
    }
#pragma unroll
    for (int j = 0; j < 4; ++j) {
        long row = m0 + g * 4;
        long col = n0 + j * 16 + r;
#pragma unroll
        for (int rr = 0; rr < 4; ++rr) {
            float v = acc[j][rr];
            if (OUTBF) ((unsigned short*)Cv)[(row + rr) * ldc + col] = f2bf(v);
            else       ((float*)Cv)[(row + rr) * ldc + col] = v;
        }
    }
}

// ---------- h0 activation ----------
__global__ void k_h0act(const float* __restrict__ hp, const float* __restrict__ bb,
                        float* __restrict__ h, unsigned short* __restrict__ hbf) {
    int i = blockIdx.x * 256 + threadIdx.x;   // 65536
    float v = my_tanh(hp[i] + bb[i & 1023]);
    h[i] = v; hbf[i] = f2bf(v);
}

// ---------- persistent step loop: 256 blocks x 1024 thr, 3 barriers/step ----------
// Round-11 structure (eh pinned in LDS) + dedup'd energy: each block computes its own
// 32 scores, exchanges via sc1 scbuf + per-batch monotonic 4-block mini-barrier.
__global__ __launch_bounds__(1024) void k_steps(
        const unsigned short* __restrict__ pk, const unsigned short* __restrict__ eh,
        const unsigned short* __restrict__ whp, const unsigned short* __restrict__ wih,
        const float* __restrict__ We, const float* __restrict__ gix,
        const float* __restrict__ bih, const float* __restrict__ bhh,
        const float* __restrict__ h0f, const unsigned short* __restrict__ hbf,
        float* __restrict__ hp, unsigned short* __restrict__ preC,
        float* __restrict__ o_states, float* __restrict__ o_hf,
        int* __restrict__ sync, float* __restrict__ scb) {
    __shared__ unsigned short ehs[S_ * 512];  // 128 KB: eh[p2_b][:, q4*512 .. +512) resident
    __shared__ float smf[16 * 64 * 4];        // 16 KB, reused per phase
    __shared__ unsigned short hsm[256];
    const int g    = blockIdx.x;
    const int tid  = threadIdx.x;
    const int wv   = tid >> 6, lane = tid & 63;
    const int r    = lane & 15, gg = lane >> 4;

    // ---- P1 roles: block = (batch-quarter, 64-col tile); wave = (col-16, k-slice) ----
    const int p1_bq = g & 3, p1_cb = g >> 2;
    const int p1_ct = wv & 3, p1_ks = wv >> 2;
    // ---- P2 roles: block = (batch, col-quarter); 4 blocks/batch on same XCD ----
    const int p2_b  = (g & 7) * 8 + (g >> 5);
    const int p2_q4 = (g >> 3) & 3;
    // ---- P3 roles: block = (j-tile, batch-group) ----
    const int jt = g >> 2, bg = g & 3;
    const int j0 = jt * 16, b0 = bg * 16;
    const int lr = tid >> 4, lc = tid & 15;
    float hreg = (tid < 256) ? h0f[(long)(b0 + lr) * 1024 + j0 + lc] : 0.f;

    // ---- one-time: stage this block's eh slice into LDS (128 rows x 512 cols bf16) ----
    {
        const unsigned short* src = eh + (long)p2_b * S_ * 2048 + p2_q4 * 512;
#pragma unroll
        for (int it = 0; it < 8; ++it) {
            int i = it * 1024 + tid;              // 8192 chunks of 8 ushorts
            int row = i >> 6, c8i = (i & 63) * 8;
            *(u16x8*)&ehs[row * 512 + c8i] = *(const u16x8*)(src + (long)row * 2048 + c8i);
        }
    }
    __syncthreads();

    int ord = 0;

#pragma unroll 1
    for (int t = 0; t < T_; ++t) {
        // ======== P1: hp[64,4096] = h_{t-1} @ whp^T ; 16 rows x 64 cols per block ========
        {
            const int n0 = p1_cb * 64 + p1_ct * 16;
            const int k0 = p1_ks * 256;
            const int b  = p1_bq * 16 + r;
            const unsigned short* arow = (t == 0)
                ? hbf + (long)b * 1024 + k0 + gg * 8
                : preC + ((long)b * T_ + (t - 1)) * 4096 + 1024 + k0 + gg * 8;   // plain
            const unsigned short* bw = whp + (long)(n0 + r) * 1024 + k0 + gg * 8;
            f32x4 acc = {};
#pragma unroll
            for (int k = 0; k < 256; k += 32) {
                bf16x8 av = *(const bf16x8*)(arow + k);
                bf16x8 bv = *(const bf16x8*)(bw + k);
                acc = __builtin_amdgcn_mfma_f32_16x16x32_bf16(av, bv, acc, 0, 0, 0);
            }
            *(f32x4*)&smf[(wv * 64 + lane) * 4] = acc;
            __syncthreads();
            if (p1_ks == 0) {   // wv == p1_ct
                f32x4 s0 = *(f32x4*)&smf[((0 * 4 + p1_ct) * 64 + lane) * 4];
                f32x4 s1 = *(f32x4*)&smf[((1 * 4 + p1_ct) * 64 + lane) * 4];
                f32x4 s2 = *(f32x4*)&smf[((2 * 4 + p1_ct) * 64 + lane) * 4];
                f32x4 s3 = *(f32x4*)&smf[((3 * 4 + p1_ct) * 64 + lane) * 4];
                f32x4 s = s0 + s1 + s2 + s3;
#pragma unroll
                for (int rr = 0; rr < 4; ++rr)
                    st4f(&hp[(long)(p1_bq * 16 + gg * 4 + rr) * 4096 + n0 + r], s[rr]);
            }
        }
        gbar(sync, g, ++ord);

        // ======== P2: attention; energy dedup'd (32 scores/block) + sc1 exchange ========
        {
            const int b = p2_b;
            // --- energy: wave wv computes scores s = q4*32 + wv*2 + {0,1}; lane: 16 h ---
            const int hh = lane * 16;
            float q[16], w16[16];
#pragma unroll
            for (int i = 0; i < 8; ++i) {
                unsigned long long u = ld8c(hp + (long)b * 4096 + hh + 2 * i);
                q[2 * i]     = __uint_as_float((unsigned)u);
                q[2 * i + 1] = __uint_as_float((unsigned)(u >> 32));
            }
#pragma unroll
            for (int i = 0; i < 16; ++i) w16[i] = We[hh + i];
#pragma unroll
            for (int k2 = 0; k2 < 2; ++k2) {
                const int s = p2_q4 * 32 + wv * 2 + k2;
                const unsigned short* row = pk + ((long)b * S_ + s) * 1024 + hh;
                u16x8 v0 = *(const u16x8*)(row);
                u16x8 v1 = *(const u16x8*)(row + 8);
                float acc = 0.f;
#pragma unroll
                for (int i = 0; i < 8; ++i) acc += my_tanh(q[i] + bf2f(v0[i])) * w16[i];
#pragma unroll
                for (int i = 0; i < 8; ++i) acc += my_tanh(q[8 + i] + bf2f(v1[i])) * w16[8 + i];
#pragma unroll
                for (int off = 32; off; off >>= 1) acc += __shfl_xor(acc, off);
                if (lane == 0) st4f(&scb[b * 128 + s], acc);
            }
            // --- 4-block mini-barrier (per-batch monotonic counter) ---
            __syncthreads();                 // drains vmcnt: score stores at coherence point
            if (tid == 0) {
                int* bc = sync + 4096 + b * 32;
                __hip_atomic_fetch_add(bc, 1, RLX, AGT);
                while (__hip_atomic_load(bc, RLX, AGT) < 4 * (t + 1))
                    __builtin_amdgcn_s_sleep(2);
            }
            __syncthreads();
            // --- softmax over 128 (threads 0..127), scores from scb (sc1) ---
            float* red = &smf[648];
            float e = 0.f, sc = 0.f;
            if (tid < 128) {
                sc = ld4f(&scb[b * 128 + tid]);
                float m = sc;
#pragma unroll
                for (int off = 32; off; off >>= 1) m = fmaxf(m, __shfl_xor(m, off));
                if ((tid & 63) == 0) red[tid >> 6] = m;
            }
            __syncthreads();
            if (tid < 128) {
                float M = fmaxf(red[0], red[1]);
                e = __expf(sc - M);
                float s = e;
#pragma unroll
                for (int off = 32; off; off >>= 1) s += __shfl_xor(s, off);
                if ((tid & 63) == 0) red[2 + (tid >> 6)] = s;
            }
            __syncthreads();
            if (tid < 128) smf[512 + tid] = e / (red[2] + red[3]);
            __syncthreads();
            // --- context: thread = (col-pair cp, s-segment sseg of 32); LDS source ---
            const int cp = tid & 255, sseg = tid >> 8;
            const unsigned short* ehp = ehs + (sseg * 32) * 512 + cp * 2;
            float a0 = 0.f, a1 = 0.f;
#pragma unroll 4
            for (int s2 = 0; s2 < 32; ++s2) {
                float alv = smf[512 + sseg * 32 + s2];
                ushort2 v = *(const ushort2*)(ehp + s2 * 512);
                a0 += alv * bf2f(v.x); a1 += alv * bf2f(v.y);
            }
            smf[1024 + (sseg * 256 + cp) * 2]     = a0;
            smf[1024 + (sseg * 256 + cp) * 2 + 1] = a1;
            __syncthreads();
            if (tid < 256) {
                float b0s = smf[1024 + tid * 2]         + smf[1024 + (256 + tid) * 2]
                          + smf[1024 + (512 + tid) * 2] + smf[1024 + (768 + tid) * 2];
                float b1s = smf[1024 + tid * 2 + 1]         + smf[1024 + (256 + tid) * 2 + 1]
                          + smf[1024 + (512 + tid) * 2 + 1] + smf[1024 + (768 + tid) * 2 + 1];
                unsigned pack = (unsigned)f2bf(b0s) | ((unsigned)f2bf(b1s) << 16);
                st4c(preC + ((long)b * T_ + t) * 4096 + 2048 + p2_q4 * 512 + tid * 2, pack);
            }
        }
        gbar(sync, g, ++ord);

        // ======== P3: gi_ctx MFMA + GRU gates; wave = (gate, k-slice of 512) ========
        {
            if (wv < 12) {
                const int c = wv >> 2, ks = wv & 3, k0 = ks * 512;
                const unsigned short* ar = preC + ((long)(b0 + r) * T_ + t) * 4096 + 2048 + k0 + gg * 8; // plain
                const unsigned short* bw = wih + ((long)(c * 1024 + j0 + r)) * 3072 + 1024 + k0 + gg * 8;
                f32x4 acc = {};
#pragma unroll
                for (int k = 0; k < 512; k += 32) {
                    bf16x8 av = *(const bf16x8*)(ar + k);
                    bf16x8 bv = *(const bf16x8*)(bw + k);
                    acc = __builtin_amdgcn_mfma_f32_16x16x32_bf16(av, bv, acc, 0, 0, 0);
                }
                *(f32x4*)&smf[(wv * 64 + lane) * 4] = acc;
            }
            __syncthreads();
            if (tid < 256) {
                const int lane_ = (lr >> 2) * 16 + lc, rr_ = lr & 3;
                float gi[3];
#pragma unroll
                for (int c = 0; c < 3; ++c) {
                    gi[c] = smf[((c * 4 + 0) * 64 + lane_) * 4 + rr_]
                          + smf[((c * 4 + 1) * 64 + lane_) * 4 + rr_]
                          + smf[((c * 4 + 2) * 64 + lane_) * 4 + rr_]
                          + smf[((c * 4 + 3) * 64 + lane_) * 4 + rr_];
                }
                const int b = b0 + lr, j = j0 + lc;
                const long bt = (long)b * T_ + t;
                float ghr = ld4f(&hp[(long)b * 4096 + 1024 + j]);
                float ghz = ld4f(&hp[(long)b * 4096 + 2048 + j]);
                float ghn = ld4f(&hp[(long)b * 4096 + 3072 + j]);
                float grv = gix[bt * 3072 + j]        + gi[0] + bih[j]        + ghr + bhh[j];
                float gzv = gix[bt * 3072 + 1024 + j] + gi[1] + bih[1024 + j] + ghz + bhh[1024 + j];
                float gni = gix[bt * 3072 + 2048 + j] + gi[2] + bih[2048 + j];
                float ghn2 = ghn + bhh[2048 + j];
                float rg = my_sig(grv);
                float zg = my_sig(gzv);
                float nv = my_tanh(gni + rg * ghn2);
                float hn = (1.f - zg) * nv + zg * hreg;
                hreg = hn;
                unsigned short hb16 = f2bf(hn);
                o_states[bt * 1024 + j] = hn;                    // plain (read after kernel)
                if (t == T_ - 1) o_hf[(long)b * 1024 + j] = hn;  // plain
                hsm[tid] = hb16;
            }
            __syncthreads();
            // pack h_t -> preC h-slot (sc1; next-step P1 reads plain)
            if (tid < 64) {
                const int plr = tid >> 2, pc4 = (tid & 3) * 4;
                unsigned long long v =
                      (unsigned long long)hsm[plr * 16 + pc4]
                    | ((unsigned long long)hsm[plr * 16 + pc4 + 1] << 16)
                    | ((unsigned long long)hsm[plr * 16 + pc4 + 2] << 32)
                    | ((unsigned long long)hsm[plr * 16 + pc4 + 3] << 48);
                st8c(preC + ((long)(b0 + plr) * T_ + t) * 4096 + 1024 + j0 + pc4, v);
            }
        }
        gbar(sync, g, ++ord);
    }
}

// ---------- host ----------
extern "C" void kernel_launch(void* const* d_in, const int* in_sizes, int n_in,
                              void* d_out, int out_size, void* d_ws, size_t ws_size,
                              hipStream_t stream) {
    const float* te  = (const float*)d_in[0];
    const float* eh  = (const float*)d_in[1];
    const float* ef  = (const float*)d_in[2];
    const float* Wb  = (const float*)d_in[5];
    const float* bb  = (const float*)d_in[6];
    const float* Wk  = (const float*)d_in[7];
    const float* Wq  = (const float*)d_in[8];
    const float* We  = (const float*)d_in[9];
    const float* Wih = (const float*)d_in[10];
    const float* Whh = (const float*)d_in[11];
    const float* bih = (const float*)d_in[12];
    const float* bhh = (const float*)d_in[13];
    const float* Wpre= (const float*)d_in[14];

    char* ws = (char*)d_ws;
    if (ws_size < 272236544UL) return;   // loud failure (output stays poisoned)
    float*          h0f   = (float*)(ws + 0);                  // 64*1024*4
    float*          hp    = (float*)(ws + 262144);             // 64*4096*4
    unsigned short* hbf   = (unsigned short*)(ws + 1310720);   // 64*1024*2 (h0 only)
    unsigned short* efb   = (unsigned short*)(ws + 1441792);   // 64*2048*2 (init only)
    int*            syncb = (int*)(ws + 1441792 + 65536);      // barrier vars + batch counters
    float*          scb   = (float*)(ws + 1572864);            // 64*128*4 score exchange
    unsigned short* ehb   = (unsigned short*)(ws + 1703936);   // B*S*2048*2
    unsigned short* pkb   = (unsigned short*)(ws + 35258368);  // B*S*1024*2
    unsigned short* preC  = (unsigned short*)(ws + 52035584);  // B*T*4096*2
    float*          gix   = (float*)(ws + 119144448);          // B*T*3072*4
    unsigned short* wbb   = (unsigned short*)(ws + 219807744); // 1024*2048*2
    unsigned short* wkb   = (unsigned short*)(ws + 224002048); // 1024*2048*2
    unsigned short* whpb  = (unsigned short*)(ws + 228196352); // 4096*1024*2
    unsigned short* wihb  = (unsigned short*)(ws + 236584960); // 3072*3072*2
    unsigned short* wpreb = (unsigned short*)(ws + 255459328); // 2048*4096*2

    float* o_states = (float*)d_out;                 // (B,T,H)
    float* o_hf     = o_states + (long)B_ * T_ * H_; // (1,B,H)
    float* o_pre    = o_hf + (long)B_ * H_;          // (B,T,2H)

    auto cvt = [&](const float* s, unsigned short* d, long n) {
        k_cvt<<<dim3((unsigned)((n / 4 + 255) / 256)), 256, 0, stream>>>(s, d, n);
    };
    cvt(eh,  ehb,  (long)B_ * S_ * 2048);
    cvt(ef,  efb,  (long)B_ * 2048);
    cvt(Wb,  wbb,  1024L * 2048);
    cvt(Wk,  wkb,  1024L * 2048);
    cvt(Wq,  whpb, 1024L * 1024);
    cvt(Whh, whpb + 1024L * 1024, 3072L * 1024);
    cvt(Wih, wihb, 3072L * 3072);
    cvt(Wpre,wpreb,2048L * 4096);
    k_cvt_te<<<8192, 256, 0, stream>>>(te, preC, (long)B_ * T_ * 1024);

    // h0 = tanh(encoder_final @ W_bridge^T + b_bridge)  (consumes efb)
    k_gemm<0><<<dim3(16, 1), 256, 0, stream>>>(efb, 2048, wbb, 2048, hp, 1024, 2048);
    k_h0act<<<256, 256, 0, stream>>>(hp, bb, h0f, hbf);
    // reset barrier vars + per-batch counters (stream-ordered, deterministic per call)
    (void)hipMemsetAsync(syncb, 0, 32768, stream);
    // proj_key = encoder_hidden @ W_key^T  (bf16 out)
    k_gemm<1><<<dim3(16, 128), 256, 0, stream>>>(ehb, 2048, wkb, 2048, pkb, 1024, 2048);
    // gi_x = trg_embed @ W_ih[:, :E]^T  (f32 out)
    k_gemm<0><<<dim3(48, 128), 256, 0, stream>>>(preC, 4096, wihb, 3072, gix, 3072, 1024);

    // persistent step loop: 256 blocks x 1024 threads, eh pinned in LDS
    k_steps<<<NBLK, 1024, 0, stream>>>(pkb, ehb, whpb, wihb, We, gix, bih, bhh,
                                       h0f, hbf, hp, preC, o_states, o_hf, syncb, scb);

    // pre_output = [x_t, h_t, ctx_t] @ W_pre^T
    k_gemm<0><<<dim3(32, 128), 256, 0, stream>>>(preC, 4096, wpreb, 4096, o_pre, 2048, 4096);
}